// Round 5
// baseline (624.761 us; speedup 1.0000x reference)
//
#include <hip/hip_runtime.h>
#include <hip/hip_cooperative_groups.h>
#include <math.h>

namespace cg = cooperative_groups;

#define CCH 128
#define BB  8
#define SLAB 16384            /* f4 elements per (b,c) slab = 65536 floats */
#define DHW 65536
#define NREG 18               /* f4 slots held in registers per thread */
#define NLDS 9                /* f4 slots held in LDS per thread */
#define NSTREAM (64 - NREG - NLDS)   /* 37: re-read in phase 3 */

typedef float f4 __attribute__((ext_vector_type(4)));

// ================= FUSED COOPERATIVE PATH =================
// pool (hold 42% of slab in reg+LDS) -> grid sync -> per-block redundant FC
// -> scale (held data free, rest re-streamed). 1024 blocks = 4/CU resident.
__global__ __launch_bounds__(256, 4) void fused_kernel(
    const float* __restrict__ x,
    const float* __restrict__ w1, const float* __restrict__ b1,
    const float* __restrict__ w2, const float* __restrict__ b2,
    float* __restrict__ out, float* __restrict__ gp)
{
    __shared__ f4    lx[NLDS * 256];   // 36864 B slab cache
    __shared__ float h[CCH];           // FC hidden layer
    __shared__ float red[4];           // wave partials
    __shared__ float gsh;              // gate broadcast

    const int bc  = blockIdx.x;        // 0..1023 = b*128+c
    const int tid = threadIdx.x;       // 0..255
    const f4* xp = (const f4*)x + (size_t)bc * SLAB + tid;

    // ---------------- Phase 1: pool max, retaining what we can ----------
    f4 r[NREG];
    float a0 = -INFINITY, a1 = -INFINITY, a2 = -INFINITY, a3 = -INFINITY;

#pragma unroll
    for (int k = 0; k < NREG; ++k) {
        f4 v = __builtin_nontemporal_load(&xp[k * 256]);
        r[k] = v;
        float mm = fmaxf(fmaxf(v.x, v.y), fmaxf(v.z, v.w));
        if ((k & 3) == 0) a0 = fmaxf(a0, mm);
        else if ((k & 3) == 1) a1 = fmaxf(a1, mm);
        else if ((k & 3) == 2) a2 = fmaxf(a2, mm);
        else a3 = fmaxf(a3, mm);
    }
#pragma unroll
    for (int k = 0; k < NLDS; ++k) {
        f4 v = __builtin_nontemporal_load(&xp[(NREG + k) * 256]);
        lx[tid + k * 256] = v;
        float mm = fmaxf(fmaxf(v.x, v.y), fmaxf(v.z, v.w));
        if ((k & 3) == 0) a0 = fmaxf(a0, mm);
        else if ((k & 3) == 1) a1 = fmaxf(a1, mm);
        else if ((k & 3) == 2) a2 = fmaxf(a2, mm);
        else a3 = fmaxf(a3, mm);
    }
#pragma unroll 8
    for (int k = 0; k < NSTREAM; ++k) {
        f4 v = __builtin_nontemporal_load(&xp[(NREG + NLDS + k) * 256]);
        float mm = fmaxf(fmaxf(v.x, v.y), fmaxf(v.z, v.w));
        if ((k & 3) == 0) a0 = fmaxf(a0, mm);
        else if ((k & 3) == 1) a1 = fmaxf(a1, mm);
        else if ((k & 3) == 2) a2 = fmaxf(a2, mm);
        else a3 = fmaxf(a3, mm);
    }
    float m = fmaxf(fmaxf(a0, a1), fmaxf(a2, a3));
#pragma unroll
    for (int off = 32; off > 0; off >>= 1)
        m = fmaxf(m, __shfl_down(m, off, 64));
    const int wave = tid >> 6, lane = tid & 63;
    if (lane == 0) red[wave] = m;
    __syncthreads();
    if (tid == 0) {
        gp[bc] = fmaxf(fmaxf(red[0], red[1]), fmaxf(red[2], red[3]));
        __threadfence();
    }

    cg::this_grid().sync();

    // ---------------- Phase 2: redundant per-block FC gate --------------
    const int b = bc >> 7, c = bc & 127;
    if (tid < CCH) {
        float acc = b1[tid];
        const float* wr  = w1 + tid * CCH;   // h[o] += w1[o][j]*gp[b][j]
        const float* gpb = gp + b * CCH;
#pragma unroll 8
        for (int j = 0; j < CCH; ++j) acc += wr[j] * gpb[j];
        h[tid] = fmaxf(acc, 0.0f);
    }
    __syncthreads();
    float p = 0.0f;
    if (tid < CCH) p = w2[c * CCH + tid] * h[tid];
#pragma unroll
    for (int off = 32; off > 0; off >>= 1) p += __shfl_down(p, off, 64);
    if (lane == 0) red[wave] = p;
    __syncthreads();
    if (tid == 0) gsh = 1.0f / (1.0f + expf(-(b2[c] + red[0] + red[1])));
    __syncthreads();
    const float gate = gsh;

    // ---------------- Phase 3: scale + store ----------------------------
    f4* op = (f4*)out + (size_t)bc * SLAB + tid;
#pragma unroll
    for (int k = 0; k < NREG; ++k) {
        f4 v = r[k]; v *= gate;
        __builtin_nontemporal_store(v, &op[k * 256]);
    }
#pragma unroll
    for (int k = 0; k < NLDS; ++k) {
        f4 v = lx[tid + k * 256]; v *= gate;
        __builtin_nontemporal_store(v, &op[(NREG + k) * 256]);
    }
#pragma unroll 8
    for (int k = 0; k < NSTREAM; ++k) {
        f4 v = __builtin_nontemporal_load(&xp[(NREG + NLDS + k) * 256]);
        v *= gate;
        __builtin_nontemporal_store(v, &op[(NREG + NLDS + k) * 256]);
    }
}

// ================= FALLBACK PATH (proven R3 kernels) =================
__global__ __launch_bounds__(256) void pool_max_kernel(
    const float* __restrict__ x, float* __restrict__ gp) {
    const int bc  = blockIdx.x;
    const int tid = threadIdx.x;
    const f4* xp = (const f4*)x + (size_t)bc * (DHW / 4);
    float m = -INFINITY;
#pragma unroll 8
    for (int k = 0; k < 64; ++k) {
        f4 v = __builtin_nontemporal_load(&xp[tid + k * 256]);
        m = fmaxf(m, fmaxf(fmaxf(v.x, v.y), fmaxf(v.z, v.w)));
    }
#pragma unroll
    for (int off = 32; off > 0; off >>= 1)
        m = fmaxf(m, __shfl_down(m, off, 64));
    __shared__ float sm[4];
    const int wave = tid >> 6, lane = tid & 63;
    if (lane == 0) sm[wave] = m;
    __syncthreads();
    if (tid == 0)
        gp[bc] = fmaxf(fmaxf(sm[0], sm[1]), fmaxf(sm[2], sm[3]));
}

__global__ __launch_bounds__(128) void fc_kernel(
    const float* __restrict__ gp,
    const float* __restrict__ w1, const float* __restrict__ b1,
    const float* __restrict__ w2, const float* __restrict__ b2,
    float* __restrict__ g) {
    __shared__ float sgp[BB][CCH];
    __shared__ float sh[BB][CCH];
    const int o = threadIdx.x;
#pragma unroll
    for (int b = 0; b < BB; ++b) sgp[b][o] = gp[b * CCH + o];
    __syncthreads();
    float acc[BB];
#pragma unroll
    for (int b = 0; b < BB; ++b) acc[b] = b1[o];
    for (int c = 0; c < CCH; ++c) {
        const float w = w1[o * CCH + c];
#pragma unroll
        for (int b = 0; b < BB; ++b) acc[b] += sgp[b][c] * w;
    }
#pragma unroll
    for (int b = 0; b < BB; ++b) sh[b][o] = fmaxf(acc[b], 0.0f);
    __syncthreads();
#pragma unroll
    for (int b = 0; b < BB; ++b) acc[b] = b2[o];
    for (int c = 0; c < CCH; ++c) {
        const float w = w2[o * CCH + c];
#pragma unroll
        for (int b = 0; b < BB; ++b) acc[b] += sh[b][c] * w;
    }
#pragma unroll
    for (int b = 0; b < BB; ++b)
        g[b * CCH + o] = 1.0f / (1.0f + expf(-acc[b]));
}

__global__ __launch_bounds__(256) void scale_kernel(
    const float* __restrict__ x, const float* __restrict__ g,
    float* __restrict__ out) {
    const int bc   = blockIdx.x >> 2;
    const int part = blockIdx.x & 3;
    const float gate = g[bc];
    const size_t base = (size_t)bc * (DHW / 4) + (size_t)part * 4096;
    const f4* xp = (const f4*)x + base;
    f4*       op = (f4*)out + base;
    const int tid = threadIdx.x;
#pragma unroll
    for (int k = 0; k < 16; ++k) {
        f4 v = __builtin_nontemporal_load(&xp[tid + k * 256]);
        v *= gate;
        __builtin_nontemporal_store(v, &op[tid + k * 256]);
    }
}

extern "C" void kernel_launch(void* const* d_in, const int* in_sizes, int n_in,
                              void* d_out, int out_size, void* d_ws, size_t ws_size,
                              hipStream_t stream) {
    const float* x  = (const float*)d_in[0];
    const float* w1 = (const float*)d_in[1];
    const float* b1 = (const float*)d_in[2];
    const float* w2 = (const float*)d_in[3];
    const float* b2 = (const float*)d_in[4];
    float* out = (float*)d_out;
    float* gp  = (float*)d_ws;          // [8*128] pooled max
    float* g   = gp + BB * CCH;         // [8*128] gate (fallback path)

    void* args[] = { (void*)&x, (void*)&w1, (void*)&b1, (void*)&w2,
                     (void*)&b2, (void*)&out, (void*)&gp };
    hipError_t err = hipLaunchCooperativeKernel(
        (const void*)fused_kernel, dim3(BB * CCH), dim3(256), args, 0, stream);

    if (err != hipSuccess) {
        // Cooperative launch unavailable (capture/validation) — proven path.
        pool_max_kernel<<<BB * CCH, 256, 0, stream>>>(x, gp);
        fc_kernel<<<1, CCH, 0, stream>>>(gp, w1, b1, w2, b2, g);
        scale_kernel<<<BB * CCH * 4, 256, 0, stream>>>(x, g, out);
    }
}

// Round 6
// 486.950 us; speedup vs baseline: 1.2830x; 1.2830x over previous
//
#include <hip/hip_runtime.h>
#include <math.h>

#define CCH 128
#define BB  8
#define SLAB 16384   /* f4 elements per (b,c) slab = 65536 floats */

typedef float f4 __attribute__((ext_vector_type(4)));

// ---------------- Kernel 1: global max over each (b,c) slab ----------------
// 1024 blocks x 512 threads: 4 blocks/CU x 8 waves = 32 waves/CU (100% occ)
// to hide the ~900cy nt-load latency. 32 f4 loads/thread covers the slab.
// nt loads: no L2/L3 allocation -> never evict the harness's dirty poison
// (eviction = writeback storm riding on our read stream).
__global__ __launch_bounds__(512) void pool_max_kernel(
    const float* __restrict__ x, float* __restrict__ gp) {
    const int bc  = blockIdx.x;                 // 0..1023
    const int tid = threadIdx.x;                // 0..511
    const f4* xp = (const f4*)x + (size_t)bc * SLAB + tid;

    float a0 = -INFINITY, a1 = -INFINITY, a2 = -INFINITY, a3 = -INFINITY;
#pragma unroll 8
    for (int k = 0; k < 32; ++k) {
        f4 v = __builtin_nontemporal_load(&xp[k * 512]);
        float mm = fmaxf(fmaxf(v.x, v.y), fmaxf(v.z, v.w));
        if ((k & 3) == 0) a0 = fmaxf(a0, mm);
        else if ((k & 3) == 1) a1 = fmaxf(a1, mm);
        else if ((k & 3) == 2) a2 = fmaxf(a2, mm);
        else a3 = fmaxf(a3, mm);
    }
    float m = fmaxf(fmaxf(a0, a1), fmaxf(a2, a3));
#pragma unroll
    for (int off = 32; off > 0; off >>= 1)
        m = fmaxf(m, __shfl_down(m, off, 64));

    __shared__ float sm[8];
    const int wave = tid >> 6, lane = tid & 63;
    if (lane == 0) sm[wave] = m;
    __syncthreads();
    if (tid == 0) {
        float r = sm[0];
#pragma unroll
        for (int w = 1; w < 8; ++w) r = fmaxf(r, sm[w]);
        gp[bc] = r;
    }
}

// ---------------- Kernel 2: fused gate-compute + scale ----------------
// 4096 blocks (4 per slab) x 256 thr = 8 blocks/CU resident, 32 waves/CU.
// Each block redundantly computes its own gate (tiny: 16K MACs, w1 is
// 64KB L2-hot across all blocks), then streams its slab quarter.
// Removes the serial 1-block fc kernel and one launch gap.
__global__ __launch_bounds__(256) void scale_fc_kernel(
    const float* __restrict__ x,  const float* __restrict__ gp,
    const float* __restrict__ w1, const float* __restrict__ b1,
    const float* __restrict__ w2, const float* __restrict__ b2,
    float* __restrict__ out) {
    const int bc   = blockIdx.x >> 2;   // 0..1023
    const int part = blockIdx.x & 3;
    const int b = bc >> 7, c = bc & 127;
    const int tid = threadIdx.x;

    __shared__ float h[CCH];
    __shared__ float red[4];
    __shared__ float gsh;

    // --- FC layer 1: h[o] = relu(b1[o] + sum_j w1[o][j] * gp[b][j]) ---
    if (tid < CCH) {
        float acc = b1[tid];
        const f4* wr = (const f4*)(w1 + tid * CCH);   // thread's w1 row
        const f4* gb = (const f4*)(gp + b * CCH);     // broadcast across wave
#pragma unroll 8
        for (int j = 0; j < CCH / 4; ++j) {
            f4 wv = wr[j], gv = gb[j];
            acc += wv.x * gv.x + wv.y * gv.y + wv.z * gv.z + wv.w * gv.w;
        }
        h[tid] = fmaxf(acc, 0.0f);
    }
    __syncthreads();

    // --- FC layer 2 (row c only): gate = sigmoid(b2[c] + w2[c]·h) ---
    float p = 0.0f;
    if (tid < CCH) p = w2[c * CCH + tid] * h[tid];
#pragma unroll
    for (int off = 32; off > 0; off >>= 1) p += __shfl_down(p, off, 64);
    const int wave = tid >> 6, lane = tid & 63;
    if (lane == 0) red[wave] = p;
    __syncthreads();
    if (tid == 0) gsh = 1.0f / (1.0f + expf(-(b2[c] + red[0] + red[1])));
    __syncthreads();
    const float gate = gsh;

    // --- stream: out = x * gate (nt both ways: no L3 allocation) ---
    const size_t base = (size_t)bc * SLAB + (size_t)part * 4096;
    const f4* xp = (const f4*)x + base;
    f4*       op = (f4*)out + base;
#pragma unroll
    for (int k = 0; k < 16; ++k) {
        f4 v = __builtin_nontemporal_load(&xp[tid + k * 256]);
        v *= gate;
        __builtin_nontemporal_store(v, &op[tid + k * 256]);
    }
}

extern "C" void kernel_launch(void* const* d_in, const int* in_sizes, int n_in,
                              void* d_out, int out_size, void* d_ws, size_t ws_size,
                              hipStream_t stream) {
    const float* x  = (const float*)d_in[0];
    const float* w1 = (const float*)d_in[1];
    const float* b1 = (const float*)d_in[2];
    const float* w2 = (const float*)d_in[3];
    const float* b2 = (const float*)d_in[4];
    float* out = (float*)d_out;
    float* gp  = (float*)d_ws;          // [8*128] pooled max

    pool_max_kernel<<<BB * CCH, 512, 0, stream>>>(x, gp);
    scale_fc_kernel<<<BB * CCH * 4, 256, 0, stream>>>(x, gp, w1, b1, w2, b2, out);
}